// Round 1
// baseline (1070.145 us; speedup 1.0000x reference)
//
#include <hip/hip_runtime.h>
#include <cstdint>
#include <cstddef>

#define B_ 4
#define C_ 256
#define N_ 4096
#define BN_TOT (B_ * N_)   // 16384

// ---------------------------------------------------------------------------
// K1: inverse L2 norms over channel dim for both tensors.
// idx in [0, 2*B*N): tensor 0 = xp, tensor 1 = xq.
// ---------------------------------------------------------------------------
__global__ __launch_bounds__(256) void norms_kernel(const float* __restrict__ xp,
                                                    const float* __restrict__ xq,
                                                    float* __restrict__ invp,
                                                    float* __restrict__ invq) {
  int idx = blockIdx.x * 256 + threadIdx.x;
  int tensor = idx >> 14;      // / 16384
  int rem = idx & 16383;
  const float* p = (tensor ? xq : xp) + (size_t)(rem >> 12) * C_ * N_ + (rem & 4095);
  float ss = 0.f;
#pragma unroll 8
  for (int ch = 0; ch < C_; ++ch) {
    float v = p[(size_t)ch * N_];
    ss = fmaf(v, v, ss);
  }
  float inv = 1.0f / fmaxf(sqrtf(ss), 1e-12f);
  (tensor ? invq : invp)[rem] = inv;
}

// ---------------------------------------------------------------------------
// K2: fp32 GEMM C[i][j] = sum_c A[c][i]*B[c][j] (both K-major), fused epilogue:
//   e = exp(alpha * invp[i] * invq[j] * dot) -> e_out (xc_o_q region)
//   rowsum[i] += sum_j e ; colsum[j] += sum_i e
// Tile 128x128, BK=8, 256 threads, 8x8 per thread.
// Epilogue sums use shfl-xor tree reductions (ZERO LDS atomics; the previous
// version did 4096 contended LDS atomicAdds per block).
// ---------------------------------------------------------------------------
#define BM 128
#define BKK 8
__global__ __launch_bounds__(256) void gemm_exp_kernel(const float* __restrict__ xp,
                                                       const float* __restrict__ xq,
                                                       const float* __restrict__ alpha_p,
                                                       const float* __restrict__ invp,
                                                       const float* __restrict__ invq,
                                                       float* __restrict__ e_out,
                                                       float* __restrict__ rowsum,
                                                       float* __restrict__ colsum) {
  __shared__ float As[BKK][BM];
  __shared__ float Bs[BKK][BM];
  __shared__ float redr[BM];        // one slot per row, written once (no atomics)
  __shared__ float redcw[4][BM];    // per-wave col partials

  const int b = blockIdx.z;
  const int i0 = blockIdx.y * BM;
  const int j0 = blockIdx.x * BM;
  const int tid = threadIdx.x;
  const int tx = tid & 15;
  const int ty = tid >> 4;
  const int wave = tid >> 6;
  const int lane = tid & 63;

  const float* A = xp + (size_t)b * C_ * N_;
  const float* Bm = xq + (size_t)b * C_ * N_;

  const int lrow = tid >> 5;         // 0..7
  const int lcol = (tid & 31) << 2;  // 0..124

  float acc[8][8];
#pragma unroll
  for (int r = 0; r < 8; ++r)
#pragma unroll
    for (int c2 = 0; c2 < 8; ++c2) acc[r][c2] = 0.f;

  for (int k0 = 0; k0 < C_; k0 += BKK) {
    float4 av = *(const float4*)&A[(size_t)(k0 + lrow) * N_ + i0 + lcol];
    float4 bv = *(const float4*)&Bm[(size_t)(k0 + lrow) * N_ + j0 + lcol];
    __syncthreads();
    *(float4*)&As[lrow][lcol] = av;
    *(float4*)&Bs[lrow][lcol] = bv;
    __syncthreads();
#pragma unroll
    for (int kk = 0; kk < BKK; ++kk) {
      float a[8], bb[8];
      *(float4*)&a[0] = *(float4*)&As[kk][ty * 8];
      *(float4*)&a[4] = *(float4*)&As[kk][ty * 8 + 4];
      *(float4*)&bb[0] = *(float4*)&Bs[kk][tx * 8];
      *(float4*)&bb[4] = *(float4*)&Bs[kk][tx * 8 + 4];
#pragma unroll
      for (int r = 0; r < 8; ++r)
#pragma unroll
        for (int c2 = 0; c2 < 8; ++c2) acc[r][c2] = fmaf(a[r], bb[c2], acc[r][c2]);
    }
  }

  // epilogue
  const float al = alpha_p[0];
  const int iBase = i0 + ty * 8;
  const int jBase = j0 + tx * 8;
  float invj[8];
#pragma unroll
  for (int c2 = 0; c2 < 8; ++c2) invj[c2] = invq[b * N_ + jBase + c2] * al;
  float csum[8];
#pragma unroll
  for (int c2 = 0; c2 < 8; ++c2) csum[c2] = 0.f;

#pragma unroll
  for (int r = 0; r < 8; ++r) {
    const int i = iBase + r;
    const float ivi = invp[b * N_ + i];
    float rs = 0.f;
    float ev[8];
#pragma unroll
    for (int c2 = 0; c2 < 8; ++c2) {
      float e = __expf(ivi * invj[c2] * acc[r][c2]);
      ev[c2] = e;
      rs += e;
      csum[c2] += e;
    }
    float* dst = e_out + (size_t)(b * N_ + i) * N_ + jBase;
    *(float4*)dst = make_float4(ev[0], ev[1], ev[2], ev[3]);
    *(float4*)(dst + 4) = make_float4(ev[4], ev[5], ev[6], ev[7]);
    // reduce rs over the 16 tx lanes sharing this row (masks 1..8 stay in-group)
    rs += __shfl_xor(rs, 1);
    rs += __shfl_xor(rs, 2);
    rs += __shfl_xor(rs, 4);
    rs += __shfl_xor(rs, 8);
    if (tx == 0) redr[ty * 8 + r] = rs;   // each (ty,r) unique per block
  }
  // reduce csum over the 4 ty values within this wave (masks 16,32)
#pragma unroll
  for (int c2 = 0; c2 < 8; ++c2) {
    csum[c2] += __shfl_xor(csum[c2], 16);
    csum[c2] += __shfl_xor(csum[c2], 32);
  }
  if (lane < 16) {
#pragma unroll
    for (int c2 = 0; c2 < 8; ++c2) redcw[wave][tx * 8 + c2] = csum[c2];
  }
  __syncthreads();
  if (tid < BM) {
    atomicAdd(&rowsum[b * N_ + i0 + tid], redr[tid]);
    atomicAdd(&colsum[b * N_ + j0 + tid],
              redcw[0][tid] + redcw[1][tid] + redcw[2][tid] + redcw[3][tid]);
  }
}

// ---------------------------------------------------------------------------
// K3: in-place reciprocal of row/col sums (2*B*N contiguous floats).
// ---------------------------------------------------------------------------
__global__ __launch_bounds__(256) void recip_kernel(float* __restrict__ v) {
  int idx = blockIdx.x * 256 + threadIdx.x;
  v[idx] = 1.0f / v[idx];
}

// ---------------------------------------------------------------------------
// Branchless sorted-triple insert: 5 min/max ops.
// ---------------------------------------------------------------------------
__device__ __forceinline__ void top3_insert(float& a0, float& a1, float& a2, float x) {
  float m0 = fmaxf(a0, x);
  float c0 = fminf(a0, x);
  float m1 = fmaxf(a1, c0);
  float c1 = fminf(a1, c0);
  float m2 = fmaxf(a2, c1);
  a0 = m0; a1 = m1; a2 = m2;
}

// ---------------------------------------------------------------------------
// K4: finalize x_c = e*e*invr[i]*invc[j], in place over the e buffer (xc_o_q),
// transposed write into xc_o_p via LDS 64x64 tile, AND fused per-tile top-3
// partials (row-wise and col-wise) so the top3 kernels never re-read the
// 2x268 MB matrices from HBM.
//   rowpart[((b*64 + jt)*3 + k)*N + i]  (jt = j0/64)  -> later merged to valp
//   colpart[((b*64 + it)*3 + k)*N + j]  (it = i0/64)  -> later merged to valq
// ---------------------------------------------------------------------------
__global__ __launch_bounds__(256) void finalize_kernel(float* __restrict__ eq,
                                                       float* __restrict__ outp,
                                                       const float* __restrict__ invr,
                                                       const float* __restrict__ invc,
                                                       float* __restrict__ rowpart,
                                                       float* __restrict__ colpart) {
  __shared__ float t[64][65];
  __shared__ float cpart[4][64][3];   // per-wave col-triple partials

  const int b = blockIdx.z;
  const int i0 = blockIdx.y * 64;
  const int j0 = blockIdx.x * 64;
  const int tid = threadIdx.x;
  const int tr = tid >> 4;          // 0..15
  const int tc = (tid & 15) << 2;   // 0..60
  const int wave = tid >> 6;
  const int lane = tid & 63;

  float ic0 = invc[b * N_ + j0 + tc + 0];
  float ic1 = invc[b * N_ + j0 + tc + 1];
  float ic2 = invc[b * N_ + j0 + tc + 2];
  float ic3 = invc[b * N_ + j0 + tc + 3];

  // col triples for this thread's 4 columns (over its 4 rows)
  float c0a[4], c1a[4], c2a[4];
#pragma unroll
  for (int c = 0; c < 4; ++c) { c0a[c] = -1e30f; c1a[c] = -1e30f; c2a[c] = -1e30f; }

  const size_t basq = (size_t)(b * N_ + i0) * N_ + j0;
#pragma unroll
  for (int rg = 0; rg < 4; ++rg) {
    const int li = rg * 16 + tr;
    const float ir = invr[b * N_ + i0 + li];
    float4 e4 = *(const float4*)(eq + basq + (size_t)li * N_ + tc);
    float4 v;
    v.x = e4.x * e4.x * ir * ic0;
    v.y = e4.y * e4.y * ir * ic1;
    v.z = e4.z * e4.z * ir * ic2;
    v.w = e4.w * e4.w * ir * ic3;
    *(float4*)(eq + basq + (size_t)li * N_ + tc) = v;
    t[tc + 0][li] = v.x;
    t[tc + 1][li] = v.y;
    t[tc + 2][li] = v.z;
    t[tc + 3][li] = v.w;

    // --- row top3 for row li over this thread's 4 cols, then over 16 tx lanes
    float r0 = -1e30f, r1 = -1e30f, r2 = -1e30f;
    top3_insert(r0, r1, r2, v.x);
    top3_insert(r0, r1, r2, v.y);
    top3_insert(r0, r1, r2, v.z);
    top3_insert(r0, r1, r2, v.w);
#pragma unroll
    for (int mask = 1; mask <= 8; mask <<= 1) {
      float b0 = __shfl_xor(r0, mask);
      float b1 = __shfl_xor(r1, mask);
      float b2 = __shfl_xor(r2, mask);
      top3_insert(r0, r1, r2, b0);
      top3_insert(r0, r1, r2, b1);
      top3_insert(r0, r1, r2, b2);
    }
    if ((tid & 15) == 0) {
      const size_t rb = ((size_t)(b * 64 + (j0 >> 6)) * 3) * N_ + i0 + li;
      rowpart[rb] = r0;
      rowpart[rb + N_] = r1;
      rowpart[rb + 2 * (size_t)N_] = r2;
    }

    // --- col triples accumulate
    top3_insert(c0a[0], c1a[0], c2a[0], v.x);
    top3_insert(c0a[1], c1a[1], c2a[1], v.y);
    top3_insert(c0a[2], c1a[2], c2a[2], v.z);
    top3_insert(c0a[3], c1a[3], c2a[3], v.w);
  }

  // reduce col triples over the 4 tr values within this wave (masks 16,32)
#pragma unroll
  for (int mask = 16; mask <= 32; mask <<= 1) {
#pragma unroll
    for (int c = 0; c < 4; ++c) {
      float b0 = __shfl_xor(c0a[c], mask);
      float b1 = __shfl_xor(c1a[c], mask);
      float b2 = __shfl_xor(c2a[c], mask);
      top3_insert(c0a[c], c1a[c], c2a[c], b0);
      top3_insert(c0a[c], c1a[c], c2a[c], b1);
      top3_insert(c0a[c], c1a[c], c2a[c], b2);
    }
  }
  if (lane < 16) {
#pragma unroll
    for (int c = 0; c < 4; ++c) {
      cpart[wave][tc + c][0] = c0a[c];
      cpart[wave][tc + c][1] = c1a[c];
      cpart[wave][tc + c][2] = c2a[c];
    }
  }

  __syncthreads();

  // transposed write of x_c into outp
  const size_t basp = (size_t)(b * N_ + j0) * N_ + i0;
#pragma unroll
  for (int cg = 0; cg < 4; ++cg) {
    const int lj = cg * 16 + tr;
    float4 v;
    v.x = t[lj][tc + 0];
    v.y = t[lj][tc + 1];
    v.z = t[lj][tc + 2];
    v.w = t[lj][tc + 3];
    *(float4*)(outp + basp + (size_t)lj * N_ + tc) = v;
  }

  // merge 4 per-wave col partials -> per-tile col top3
  if (tid < 64) {
    float a0 = -1e30f, a1 = -1e30f, a2 = -1e30f;
#pragma unroll
    for (int w = 0; w < 4; ++w) {
      top3_insert(a0, a1, a2, cpart[w][tid][0]);
      top3_insert(a0, a1, a2, cpart[w][tid][1]);
      top3_insert(a0, a1, a2, cpart[w][tid][2]);
    }
    const size_t cb = ((size_t)(b * 64 + (i0 >> 6)) * 3) * N_ + j0 + tid;
    colpart[cb] = a0;
    colpart[cb + N_] = a1;
    colpart[cb + 2 * (size_t)N_] = a2;
  }
}

// ---------------------------------------------------------------------------
// K5: merge 64 per-tile top3 partials per (b, r) into final top3.
// One wave per (which, b, r): which=0 -> rows -> valp, which=1 -> cols -> valq.
// Partials are L2/L3-resident (just written, 25 MB total).
// ---------------------------------------------------------------------------
__global__ __launch_bounds__(256) void top3_merge_kernel(const float* __restrict__ rowpart,
                                                         const float* __restrict__ colpart,
                                                         float* __restrict__ valp,
                                                         float* __restrict__ valq) {
  const int wid = blockIdx.x * 4 + (threadIdx.x >> 6);  // 0..32767
  const int lane = threadIdx.x & 63;
  const int which = wid >> 14;        // 0 = rows, 1 = cols
  const int rem = wid & 16383;
  const int b = rem >> 12;
  const int r = rem & 4095;
  const float* part = which ? colpart : rowpart;

  float a0 = -1e30f, a1 = -1e30f, a2 = -1e30f;
  const float* p = part + ((size_t)(b * 64 + lane) * 3) * N_ + r;  // lane = tile
  top3_insert(a0, a1, a2, p[0]);
  top3_insert(a0, a1, a2, p[N_]);
  top3_insert(a0, a1, a2, p[2 * (size_t)N_]);
#pragma unroll
  for (int mask = 1; mask <= 32; mask <<= 1) {
    float b0 = __shfl_xor(a0, mask);
    float b1 = __shfl_xor(a1, mask);
    float b2 = __shfl_xor(a2, mask);
    top3_insert(a0, a1, a2, b0);
    top3_insert(a0, a1, a2, b1);
    top3_insert(a0, a1, a2, b2);
  }
  if (lane == 0) {
    float* out = which ? valq : valp;
    out[(b * 3 + 0) * N_ + r] = a0;
    out[(b * 3 + 1) * N_ + r] = a1;
    out[(b * 3 + 2) * N_ + r] = a2;
  }
}

// ---------------------------------------------------------------------------
extern "C" void kernel_launch(void* const* d_in, const int* in_sizes, int n_in,
                              void* d_out, int out_size, void* d_ws, size_t ws_size,
                              hipStream_t stream) {
  const float* xp = (const float*)d_in[0];
  const float* xq = (const float*)d_in[1];
  const float* alpha = (const float*)d_in[2];

  float* o = (float*)d_out;
  float* valp = o;                               // [4,3,64,64]   = 49152
  float* valq = o + 49152;                       // [4,3,64,64]   = 49152
  float* xcp = o + 98304;                        // [4,4096,64,64]= 67108864
  float* xcq = o + 98304 + 67108864;             // [4,4096,64,64]

  float* wsf = (float*)d_ws;
  float* invp = wsf;                         // 16384
  float* invq = wsf + 16384;                 // 16384
  float* rowsum = wsf + 32768;               // 16384
  float* colsum = wsf + 49152;               // 16384
  float* rowpart = wsf + 65536;              // 4*64*3*4096 = 3145728
  float* colpart = wsf + 65536 + 3145728;    // 3145728  (ws total ~25.4 MB)

  hipMemsetAsync(rowsum, 0, (size_t)2 * BN_TOT * sizeof(float), stream);

  norms_kernel<<<2 * BN_TOT / 256, 256, 0, stream>>>(xp, xq, invp, invq);

  gemm_exp_kernel<<<dim3(N_ / BM, N_ / BM, B_), 256, 0, stream>>>(
      xp, xq, alpha, invp, invq, xcq, rowsum, colsum);

  recip_kernel<<<2 * BN_TOT / 256, 256, 0, stream>>>(rowsum);  // rowsum+colsum contiguous

  finalize_kernel<<<dim3(N_ / 64, N_ / 64, B_), 256, 0, stream>>>(
      xcq, xcp, rowsum, colsum, rowpart, colpart);

  top3_merge_kernel<<<2 * BN_TOT / 4, 256, 0, stream>>>(rowpart, colpart, valp, valq);
}

// Round 2
// 836.475 us; speedup vs baseline: 1.2794x; 1.2794x over previous
//
#include <hip/hip_runtime.h>
#include <cstdint>
#include <cstddef>

#define B_ 4
#define C_ 256
#define N_ 4096
#define BN_TOT (B_ * N_)   // 16384

typedef _Float16 f16x8 __attribute__((ext_vector_type(8)));
typedef _Float16 f16x4 __attribute__((ext_vector_type(4)));
typedef float f32x4 __attribute__((ext_vector_type(4)));

// ---------------------------------------------------------------------------
// K1: inverse L2 norms over channel dim for both tensors.
// ---------------------------------------------------------------------------
__global__ __launch_bounds__(256) void norms_kernel(const float* __restrict__ xp,
                                                    const float* __restrict__ xq,
                                                    float* __restrict__ invp,
                                                    float* __restrict__ invq) {
  int idx = blockIdx.x * 256 + threadIdx.x;
  int tensor = idx >> 14;      // / 16384
  int rem = idx & 16383;
  const float* p = (tensor ? xq : xp) + (size_t)(rem >> 12) * C_ * N_ + (rem & 4095);
  float ss = 0.f;
#pragma unroll 16
  for (int ch = 0; ch < C_; ++ch) {
    float v = p[(size_t)ch * N_];
    ss = fmaf(v, v, ss);
  }
  float inv = 1.0f / fmaxf(sqrtf(ss), 1e-12f);
  (tensor ? invq : invp)[rem] = inv;
}

// ---------------------------------------------------------------------------
// K2: normalize + split into fp16 hi/lo (lo scaled by 1024) + transpose
// [c][i] fp32 -> [i][c] fp16, per (tensor, b). 64x64 tiles via LDS.
// ---------------------------------------------------------------------------
__global__ __launch_bounds__(256) void convert_kernel(const float* __restrict__ xp,
                                                      const float* __restrict__ xq,
                                                      const float* __restrict__ invp,
                                                      const float* __restrict__ invq,
                                                      _Float16* __restrict__ ph,
                                                      _Float16* __restrict__ pl,
                                                      _Float16* __restrict__ qh,
                                                      _Float16* __restrict__ ql) {
  __shared__ _Float16 ht[64][72];
  __shared__ _Float16 lt[64][72];
  const int tensor = blockIdx.z & 1;
  const int b = blockIdx.z >> 1;
  const int i0 = blockIdx.x * 64;
  const int c0 = blockIdx.y * 64;
  const int tid = threadIdx.x;
  const int si = tid & 15;   // i sub-block
  const int sc = tid >> 4;   // c sub-block
  const float* x = (tensor ? xq : xp) + (size_t)b * C_ * N_;
  const float* inv = (tensor ? invq : invp) + b * N_;
  _Float16* oh = (tensor ? qh : ph) + (size_t)b * N_ * C_;
  _Float16* ol = (tensor ? ql : pl) + (size_t)b * N_ * C_;

  float4 iv = *(const float4*)&inv[i0 + si * 4];

  _Float16 hv[4][4], lv[4][4];   // [rr = c][u = i]
#pragma unroll
  for (int rr = 0; rr < 4; ++rr) {
    float4 v = *(const float4*)&x[(size_t)(c0 + sc * 4 + rr) * N_ + i0 + si * 4];
    float f0 = v.x * iv.x, f1 = v.y * iv.y, f2 = v.z * iv.z, f3 = v.w * iv.w;
    _Float16 h0 = (_Float16)f0, h1 = (_Float16)f1, h2 = (_Float16)f2, h3 = (_Float16)f3;
    hv[rr][0] = h0; lv[rr][0] = (_Float16)((f0 - (float)h0) * 1024.f);
    hv[rr][1] = h1; lv[rr][1] = (_Float16)((f1 - (float)h1) * 1024.f);
    hv[rr][2] = h2; lv[rr][2] = (_Float16)((f2 - (float)h2) * 1024.f);
    hv[rr][3] = h3; lv[rr][3] = (_Float16)((f3 - (float)h3) * 1024.f);
  }
#pragma unroll
  for (int u = 0; u < 4; ++u) {
    f16x4 th = {hv[0][u], hv[1][u], hv[2][u], hv[3][u]};
    f16x4 tl = {lv[0][u], lv[1][u], lv[2][u], lv[3][u]};
    *(f16x4*)&ht[si * 4 + u][sc * 4] = th;
    *(f16x4*)&lt[si * 4 + u][sc * 4] = tl;
  }
  __syncthreads();
  const int ir = tid >> 2;
  const int ch = tid & 3;
  f16x8 h0 = *(const f16x8*)&ht[ir][ch * 16];
  f16x8 h1 = *(const f16x8*)&ht[ir][ch * 16 + 8];
  f16x8 l0 = *(const f16x8*)&lt[ir][ch * 16];
  f16x8 l1 = *(const f16x8*)&lt[ir][ch * 16 + 8];
  _Float16* po = oh + (size_t)(i0 + ir) * C_ + c0 + ch * 16;
  *(f16x8*)po = h0;
  *(f16x8*)(po + 8) = h1;
  _Float16* po2 = ol + (size_t)(i0 + ir) * C_ + c0 + ch * 16;
  *(f16x8*)po2 = l0;
  *(f16x8*)(po2 + 8) = l1;
}

// ---------------------------------------------------------------------------
// K3: MFMA GEMM with split-fp16 x3 emulation of fp32:
//   dot = hi.hi + (hi.lo + lo.hi)/1024
// Tile 128x128xBK32, 256 threads = 4 waves (2x2 grid of 64x64 per wave),
// mfma_f32_16x16x32_f16 (4x4 frags x 3 products = 48 MFMA per wave/K-step).
// Fused epilogue: e = exp(alpha*dot) -> e_out; row/col sums via shfl + LDS.
// ---------------------------------------------------------------------------
__global__ __launch_bounds__(256, 2) void gemm_mfma_kernel(
    const _Float16* __restrict__ ph, const _Float16* __restrict__ pl,
    const _Float16* __restrict__ qh, const _Float16* __restrict__ ql,
    const float* __restrict__ alpha_p,
    float* __restrict__ e_out,
    float* __restrict__ rowsum, float* __restrict__ colsum) {
  __shared__ _Float16 Ah[128][40];
  __shared__ _Float16 Al[128][40];
  __shared__ _Float16 Bh[128][40];
  __shared__ _Float16 Bl[128][40];
  __shared__ float redr[2][128];
  __shared__ float redc[2][128];

  const int b = blockIdx.z;
  const int i0 = blockIdx.y * 128;
  const int j0 = blockIdx.x * 128;
  const int tid = threadIdx.x;
  const int lane = tid & 63;
  const int wave = tid >> 6;
  const int wr = wave >> 1;   // 0..1
  const int wc = wave & 1;    // 0..1

  const size_t tb = (size_t)b * N_ * C_;
  const _Float16* pAh = ph + tb + (size_t)(i0 + (tid >> 1)) * C_ + (tid & 1) * 16;
  const _Float16* pAl = pl + tb + (size_t)(i0 + (tid >> 1)) * C_ + (tid & 1) * 16;
  const _Float16* pBh = qh + tb + (size_t)(j0 + (tid >> 1)) * C_ + (tid & 1) * 16;
  const _Float16* pBl = ql + tb + (size_t)(j0 + (tid >> 1)) * C_ + (tid & 1) * 16;

  _Float16* wAh = &Ah[tid >> 1][(tid & 1) * 16];
  _Float16* wAl = &Al[tid >> 1][(tid & 1) * 16];
  _Float16* wBh = &Bh[tid >> 1][(tid & 1) * 16];
  _Float16* wBl = &Bl[tid >> 1][(tid & 1) * 16];

  f32x4 acc_hh[4][4], acc_m[4][4];
#pragma unroll
  for (int m = 0; m < 4; ++m)
#pragma unroll
    for (int n = 0; n < 4; ++n) {
      acc_hh[m][n] = (f32x4){0.f, 0.f, 0.f, 0.f};
      acc_m[m][n] = (f32x4){0.f, 0.f, 0.f, 0.f};
    }

  const int frow = lane & 15;
  const int fk = (lane >> 4) * 8;

  for (int k0 = 0; k0 < C_; k0 += 32) {
    f16x8 ra0 = *(const f16x8*)(pAh + k0);
    f16x8 ra1 = *(const f16x8*)(pAh + k0 + 8);
    f16x8 rb0 = *(const f16x8*)(pAl + k0);
    f16x8 rb1 = *(const f16x8*)(pAl + k0 + 8);
    f16x8 rc0 = *(const f16x8*)(pBh + k0);
    f16x8 rc1 = *(const f16x8*)(pBh + k0 + 8);
    f16x8 rd0 = *(const f16x8*)(pBl + k0);
    f16x8 rd1 = *(const f16x8*)(pBl + k0 + 8);
    __syncthreads();
    *(f16x8*)wAh = ra0; *(f16x8*)(wAh + 8) = ra1;
    *(f16x8*)wAl = rb0; *(f16x8*)(wAl + 8) = rb1;
    *(f16x8*)wBh = rc0; *(f16x8*)(wBh + 8) = rc1;
    *(f16x8*)wBl = rd0; *(f16x8*)(wBl + 8) = rd1;
    __syncthreads();

    f16x8 fah[4], fal[4], fbh[4], fbl[4];
#pragma unroll
    for (int m = 0; m < 4; ++m) {
      fah[m] = *(const f16x8*)&Ah[wr * 64 + m * 16 + frow][fk];
      fal[m] = *(const f16x8*)&Al[wr * 64 + m * 16 + frow][fk];
    }
#pragma unroll
    for (int n = 0; n < 4; ++n) {
      fbh[n] = *(const f16x8*)&Bh[wc * 64 + n * 16 + frow][fk];
      fbl[n] = *(const f16x8*)&Bl[wc * 64 + n * 16 + frow][fk];
    }
#pragma unroll
    for (int m = 0; m < 4; ++m)
#pragma unroll
      for (int n = 0; n < 4; ++n) {
        acc_hh[m][n] = __builtin_amdgcn_mfma_f32_16x16x32_f16(fah[m], fbh[n], acc_hh[m][n], 0, 0, 0);
        acc_m[m][n]  = __builtin_amdgcn_mfma_f32_16x16x32_f16(fah[m], fbl[n], acc_m[m][n], 0, 0, 0);
        acc_m[m][n]  = __builtin_amdgcn_mfma_f32_16x16x32_f16(fal[m], fbh[n], acc_m[m][n], 0, 0, 0);
      }
  }

  // ---- epilogue: e = exp(alpha*dot); write e; row/col partial sums
  const float al = alpha_p[0];
  float rowp[4][4];
  float colp[4];
#pragma unroll
  for (int m = 0; m < 4; ++m)
#pragma unroll
    for (int r = 0; r < 4; ++r) rowp[m][r] = 0.f;
#pragma unroll
  for (int n = 0; n < 4; ++n) colp[n] = 0.f;

  const int rbase = i0 + wr * 64;
  const int cbase = j0 + wc * 64;
  const int rlane = (lane >> 4) * 4;   // row group from C/D layout
  const int clane = lane & 15;         // col from C/D layout

#pragma unroll
  for (int m = 0; m < 4; ++m)
#pragma unroll
    for (int n = 0; n < 4; ++n) {
      f32x4 dh = acc_hh[m][n];
      f32x4 dm = acc_m[m][n];
#pragma unroll
      for (int reg = 0; reg < 4; ++reg) {
        float dot = dh[reg] + dm[reg] * (1.f / 1024.f);
        float e = __expf(al * dot);
        int row = rbase + m * 16 + rlane + reg;
        int col = cbase + n * 16 + clane;
        e_out[(size_t)(b * N_ + row) * N_ + col] = e;
        rowp[m][reg] += e;
        colp[n] += e;
      }
    }

#pragma unroll
  for (int m = 0; m < 4; ++m)
#pragma unroll
    for (int reg = 0; reg < 4; ++reg) {
      float r = rowp[m][reg];
      r += __shfl_xor(r, 1);
      r += __shfl_xor(r, 2);
      r += __shfl_xor(r, 4);
      r += __shfl_xor(r, 8);
      if (clane == 0) redr[wc][wr * 64 + m * 16 + rlane + reg] = r;
    }
#pragma unroll
  for (int n = 0; n < 4; ++n) {
    float c = colp[n];
    c += __shfl_xor(c, 16);
    c += __shfl_xor(c, 32);
    if (lane < 16) redc[wr][wc * 64 + n * 16 + clane] = c;
  }
  __syncthreads();
  if (tid < 128) {
    atomicAdd(&rowsum[b * N_ + i0 + tid], redr[0][tid] + redr[1][tid]);
    atomicAdd(&colsum[b * N_ + j0 + tid], redc[0][tid] + redc[1][tid]);
  }
}

// ---------------------------------------------------------------------------
// K4: in-place reciprocal of row/col sums (2*B*N contiguous floats).
// ---------------------------------------------------------------------------
__global__ __launch_bounds__(256) void recip_kernel(float* __restrict__ v) {
  int idx = blockIdx.x * 256 + threadIdx.x;
  v[idx] = 1.0f / v[idx];
}

// ---------------------------------------------------------------------------
// Branchless sorted-triple insert: 5 min/max ops.
// ---------------------------------------------------------------------------
__device__ __forceinline__ void top3_insert(float& a0, float& a1, float& a2, float x) {
  float m0 = fmaxf(a0, x);
  float c0 = fminf(a0, x);
  float m1 = fmaxf(a1, c0);
  float c1 = fminf(a1, c0);
  float m2 = fmaxf(a2, c1);
  a0 = m0; a1 = m1; a2 = m2;
}

// ---------------------------------------------------------------------------
// K5: finalize x_c = e*e*invr[i]*invc[j], in place over the e buffer (xc_o_q),
// transposed write into xc_o_p via LDS 64x64 tile, fused per-tile top-3
// partials (row-wise and col-wise).
// ---------------------------------------------------------------------------
__global__ __launch_bounds__(256) void finalize_kernel(float* __restrict__ eq,
                                                       float* __restrict__ outp,
                                                       const float* __restrict__ invr,
                                                       const float* __restrict__ invc,
                                                       float* __restrict__ rowpart,
                                                       float* __restrict__ colpart) {
  __shared__ float t[64][65];
  __shared__ float cpart[4][64][3];

  const int b = blockIdx.z;
  const int i0 = blockIdx.y * 64;
  const int j0 = blockIdx.x * 64;
  const int tid = threadIdx.x;
  const int tr = tid >> 4;          // 0..15
  const int tc = (tid & 15) << 2;   // 0..60
  const int wave = tid >> 6;
  const int lane = tid & 63;

  float ic0 = invc[b * N_ + j0 + tc + 0];
  float ic1 = invc[b * N_ + j0 + tc + 1];
  float ic2 = invc[b * N_ + j0 + tc + 2];
  float ic3 = invc[b * N_ + j0 + tc + 3];

  float c0a[4], c1a[4], c2a[4];
#pragma unroll
  for (int c = 0; c < 4; ++c) { c0a[c] = -1e30f; c1a[c] = -1e30f; c2a[c] = -1e30f; }

  const size_t basq = (size_t)(b * N_ + i0) * N_ + j0;
#pragma unroll
  for (int rg = 0; rg < 4; ++rg) {
    const int li = rg * 16 + tr;
    const float ir = invr[b * N_ + i0 + li];
    float4 e4 = *(const float4*)(eq + basq + (size_t)li * N_ + tc);
    float4 v;
    v.x = e4.x * e4.x * ir * ic0;
    v.y = e4.y * e4.y * ir * ic1;
    v.z = e4.z * e4.z * ir * ic2;
    v.w = e4.w * e4.w * ir * ic3;
    *(float4*)(eq + basq + (size_t)li * N_ + tc) = v;
    t[tc + 0][li] = v.x;
    t[tc + 1][li] = v.y;
    t[tc + 2][li] = v.z;
    t[tc + 3][li] = v.w;

    float r0 = -1e30f, r1 = -1e30f, r2 = -1e30f;
    top3_insert(r0, r1, r2, v.x);
    top3_insert(r0, r1, r2, v.y);
    top3_insert(r0, r1, r2, v.z);
    top3_insert(r0, r1, r2, v.w);
#pragma unroll
    for (int mask = 1; mask <= 8; mask <<= 1) {
      float b0 = __shfl_xor(r0, mask);
      float b1 = __shfl_xor(r1, mask);
      float b2 = __shfl_xor(r2, mask);
      top3_insert(r0, r1, r2, b0);
      top3_insert(r0, r1, r2, b1);
      top3_insert(r0, r1, r2, b2);
    }
    if ((tid & 15) == 0) {
      const size_t rb = ((size_t)(b * 64 + (j0 >> 6)) * 3) * N_ + i0 + li;
      rowpart[rb] = r0;
      rowpart[rb + N_] = r1;
      rowpart[rb + 2 * (size_t)N_] = r2;
    }

    top3_insert(c0a[0], c1a[0], c2a[0], v.x);
    top3_insert(c0a[1], c1a[1], c2a[1], v.y);
    top3_insert(c0a[2], c1a[2], c2a[2], v.z);
    top3_insert(c0a[3], c1a[3], c2a[3], v.w);
  }

#pragma unroll
  for (int mask = 16; mask <= 32; mask <<= 1) {
#pragma unroll
    for (int c = 0; c < 4; ++c) {
      float b0 = __shfl_xor(c0a[c], mask);
      float b1 = __shfl_xor(c1a[c], mask);
      float b2 = __shfl_xor(c2a[c], mask);
      top3_insert(c0a[c], c1a[c], c2a[c], b0);
      top3_insert(c0a[c], c1a[c], c2a[c], b1);
      top3_insert(c0a[c], c1a[c], c2a[c], b2);
    }
  }
  if (lane < 16) {
#pragma unroll
    for (int c = 0; c < 4; ++c) {
      cpart[wave][tc + c][0] = c0a[c];
      cpart[wave][tc + c][1] = c1a[c];
      cpart[wave][tc + c][2] = c2a[c];
    }
  }

  __syncthreads();

  const size_t basp = (size_t)(b * N_ + j0) * N_ + i0;
#pragma unroll
  for (int cg = 0; cg < 4; ++cg) {
    const int lj = cg * 16 + tr;
    float4 v;
    v.x = t[lj][tc + 0];
    v.y = t[lj][tc + 1];
    v.z = t[lj][tc + 2];
    v.w = t[lj][tc + 3];
    *(float4*)(outp + basp + (size_t)lj * N_ + tc) = v;
  }

  if (tid < 64) {
    float a0 = -1e30f, a1 = -1e30f, a2 = -1e30f;
#pragma unroll
    for (int w = 0; w < 4; ++w) {
      top3_insert(a0, a1, a2, cpart[w][tid][0]);
      top3_insert(a0, a1, a2, cpart[w][tid][1]);
      top3_insert(a0, a1, a2, cpart[w][tid][2]);
    }
    const size_t cb = ((size_t)(b * 64 + (i0 >> 6)) * 3) * N_ + j0 + tid;
    colpart[cb] = a0;
    colpart[cb + N_] = a1;
    colpart[cb + 2 * (size_t)N_] = a2;
  }
}

// ---------------------------------------------------------------------------
// K6: merge 64 per-tile top3 partials per (b, r). Thread-per-output-r,
// fully coalesced (previous version read at 48 KB lane stride).
// ---------------------------------------------------------------------------
__global__ __launch_bounds__(256) void top3_merge_kernel(const float* __restrict__ rowpart,
                                                         const float* __restrict__ colpart,
                                                         float* __restrict__ valp,
                                                         float* __restrict__ valq) {
  const int gid = blockIdx.x * 256 + threadIdx.x;   // 0..32767
  const int which = gid >> 14;        // 0 = rows -> valp, 1 = cols -> valq
  const int rem = gid & 16383;
  const int b = rem >> 12;
  const int r = rem & 4095;
  const float* part = (which ? colpart : rowpart) + (size_t)(b * 64) * 3 * N_ + r;

  float a0 = -1e30f, a1 = -1e30f, a2 = -1e30f;
#pragma unroll 4
  for (int t = 0; t < 192; ++t) {     // 64 tiles x 3 ranks
    top3_insert(a0, a1, a2, part[0]);
    part += N_;
  }
  float* out = which ? valq : valp;
  out[(b * 3 + 0) * N_ + r] = a0;
  out[(b * 3 + 1) * N_ + r] = a1;
  out[(b * 3 + 2) * N_ + r] = a2;
}

// ---------------------------------------------------------------------------
extern "C" void kernel_launch(void* const* d_in, const int* in_sizes, int n_in,
                              void* d_out, int out_size, void* d_ws, size_t ws_size,
                              hipStream_t stream) {
  const float* xp = (const float*)d_in[0];
  const float* xq = (const float*)d_in[1];
  const float* alpha = (const float*)d_in[2];

  float* o = (float*)d_out;
  float* valp = o;                               // [4,3,64,64]
  float* valq = o + 49152;                       // [4,3,64,64]
  float* xcp = o + 98304;                        // [4,4096,64,64]
  float* xcq = o + 98304 + 67108864;             // [4,4096,64,64]

  float* wsf = (float*)d_ws;
  float* invp = wsf;                  // 16384
  float* invq = wsf + 16384;          // 16384
  float* rowsum = wsf + 32768;        // 16384
  float* colsum = wsf + 49152;        // 16384
  // fp16 hi/lo buffers (used convert->gemm) alias the top3 partial buffers
  // (used finalize->merge); lifetimes are disjoint in stream order.
  char* dyn = (char*)(wsf + 65536);
  _Float16* ph = (_Float16*)dyn;                       // 4*4096*256 halves
  _Float16* pl = ph + (size_t)B_ * N_ * C_;
  _Float16* qh = pl + (size_t)B_ * N_ * C_;
  _Float16* ql = qh + (size_t)B_ * N_ * C_;            // total 33.55 MB
  float* rowpart = (float*)dyn;                        // 12.58 MB
  float* colpart = rowpart + 3145728;                  // 12.58 MB

  hipMemsetAsync(rowsum, 0, (size_t)2 * BN_TOT * sizeof(float), stream);

  norms_kernel<<<2 * BN_TOT / 256, 256, 0, stream>>>(xp, xq, invp, invq);

  convert_kernel<<<dim3(N_ / 64, C_ / 64, 2 * B_), 256, 0, stream>>>(
      xp, xq, invp, invq, ph, pl, qh, ql);

  gemm_mfma_kernel<<<dim3(N_ / 128, N_ / 128, B_), 256, 0, stream>>>(
      ph, pl, qh, ql, alpha, xcq, rowsum, colsum);

  recip_kernel<<<2 * BN_TOT / 256, 256, 0, stream>>>(rowsum);  // rowsum+colsum contiguous

  finalize_kernel<<<dim3(N_ / 64, N_ / 64, B_), 256, 0, stream>>>(
      xcq, xcp, rowsum, colsum, rowpart, colpart);

  top3_merge_kernel<<<2 * BN_TOT / 256, 256, 0, stream>>>(rowpart, colpart, valp, valq);
}

// Round 4
// 785.744 us; speedup vs baseline: 1.3620x; 1.0646x over previous
//
#include <hip/hip_runtime.h>
#include <cstdint>
#include <cstddef>

#define B_ 4
#define C_ 256
#define N_ 4096
#define BN_TOT (B_ * N_)   // 16384

typedef _Float16 f16x8 __attribute__((ext_vector_type(8)));
typedef _Float16 f16x4 __attribute__((ext_vector_type(4)));
typedef float f32x4 __attribute__((ext_vector_type(4)));

// ---------------------------------------------------------------------------
// K1: fused norms + split + transpose.
// One block per (tensor, b, 64-row i-panel): reads the full 64x256 fp32 panel
// into registers, computes inv L2 norms in-block (LDS reduce), then emits
// normalized hi/lo fp16 (lo scaled by 1024) transposed to [i][c] layout.
// ---------------------------------------------------------------------------
__global__ __launch_bounds__(256) void convert_kernel(const float* __restrict__ xp,
                                                      const float* __restrict__ xq,
                                                      _Float16* __restrict__ ph,
                                                      _Float16* __restrict__ pl,
                                                      _Float16* __restrict__ qh,
                                                      _Float16* __restrict__ ql) {
  __shared__ _Float16 ht[64][72];
  __shared__ _Float16 lt[64][72];
  __shared__ float red[16][64];
  __shared__ float invs[64];
  const int tensor = blockIdx.z & 1;
  const int b = blockIdx.z >> 1;
  const int i0 = blockIdx.x * 64;
  const int tid = threadIdx.x;
  const int si = tid & 15;   // i sub-group (4 i's each)
  const int sc = tid >> 4;   // c sub-group (4 c's per cb block)
  const float* x = (tensor ? xq : xp) + (size_t)b * C_ * N_;
  _Float16* oh = (tensor ? qh : ph) + (size_t)b * N_ * C_;
  _Float16* ol = (tensor ? ql : pl) + (size_t)b * N_ * C_;

  // Pass A: load the whole 64x256 panel (this thread: 16 c-rows x 4 i-cols),
  // accumulating per-column sum of squares.
  float4 data[4][4];   // [cb][rr]
  float ss0 = 0.f, ss1 = 0.f, ss2 = 0.f, ss3 = 0.f;
#pragma unroll
  for (int cb = 0; cb < 4; ++cb)
#pragma unroll
    for (int rr = 0; rr < 4; ++rr) {
      float4 v = *(const float4*)&x[(size_t)(cb * 64 + sc * 4 + rr) * N_ + i0 + si * 4];
      data[cb][rr] = v;
      ss0 = fmaf(v.x, v.x, ss0);
      ss1 = fmaf(v.y, v.y, ss1);
      ss2 = fmaf(v.z, v.z, ss2);
      ss3 = fmaf(v.w, v.w, ss3);
    }
  red[sc][si * 4 + 0] = ss0;
  red[sc][si * 4 + 1] = ss1;
  red[sc][si * 4 + 2] = ss2;
  red[sc][si * 4 + 3] = ss3;
  __syncthreads();
  if (tid < 64) {
    float s = 0.f;
#pragma unroll
    for (int w = 0; w < 16; ++w) s += red[w][tid];
    invs[tid] = 1.0f / fmaxf(sqrtf(s), 1e-12f);
  }
  __syncthreads();
  const float iv0 = invs[si * 4 + 0];
  const float iv1 = invs[si * 4 + 1];
  const float iv2 = invs[si * 4 + 2];
  const float iv3 = invs[si * 4 + 3];

  // Pass B: per 64-c block: split to hi/lo, transpose via LDS, store [i][c].
#pragma unroll
  for (int cb = 0; cb < 4; ++cb) {
    _Float16 hv[4][4], lv[4][4];   // [rr = c][u = i]
#pragma unroll
    for (int rr = 0; rr < 4; ++rr) {
      float4 v = data[cb][rr];
      float f0 = v.x * iv0, f1 = v.y * iv1, f2 = v.z * iv2, f3 = v.w * iv3;
      _Float16 h0 = (_Float16)f0, h1 = (_Float16)f1, h2 = (_Float16)f2, h3 = (_Float16)f3;
      hv[rr][0] = h0; lv[rr][0] = (_Float16)((f0 - (float)h0) * 1024.f);
      hv[rr][1] = h1; lv[rr][1] = (_Float16)((f1 - (float)h1) * 1024.f);
      hv[rr][2] = h2; lv[rr][2] = (_Float16)((f2 - (float)h2) * 1024.f);
      hv[rr][3] = h3; lv[rr][3] = (_Float16)((f3 - (float)h3) * 1024.f);
    }
#pragma unroll
    for (int u = 0; u < 4; ++u) {
      f16x4 th = {hv[0][u], hv[1][u], hv[2][u], hv[3][u]};
      f16x4 tl = {lv[0][u], lv[1][u], lv[2][u], lv[3][u]};
      *(f16x4*)&ht[si * 4 + u][sc * 4] = th;
      *(f16x4*)&lt[si * 4 + u][sc * 4] = tl;
    }
    __syncthreads();
    const int ir = tid >> 2;
    const int ch = tid & 3;
    f16x8 h0 = *(const f16x8*)&ht[ir][ch * 16];
    f16x8 h1 = *(const f16x8*)&ht[ir][ch * 16 + 8];
    f16x8 l0 = *(const f16x8*)&lt[ir][ch * 16];
    f16x8 l1 = *(const f16x8*)&lt[ir][ch * 16 + 8];
    _Float16* po = oh + (size_t)(i0 + ir) * C_ + cb * 64 + ch * 16;
    *(f16x8*)po = h0;
    *(f16x8*)(po + 8) = h1;
    _Float16* po2 = ol + (size_t)(i0 + ir) * C_ + cb * 64 + ch * 16;
    *(f16x8*)po2 = l0;
    *(f16x8*)(po2 + 8) = l1;
    __syncthreads();   // ht/lt reused next cb
  }
}

// ---------------------------------------------------------------------------
// K2: MFMA GEMM, split-fp16 x3 emulation: dot = hi.hi + (hi.lo + lo.hi)/1024.
// 128x128 tile, BK=32, 4 waves (2x2 of 64x64). Double-buffered LDS (one
// barrier per K-step), reg-prefetch of next K-step, setprio around MFMA,
// bijective XCD-aware block swizzle.
// ---------------------------------------------------------------------------
#define PADK 36
__global__ __launch_bounds__(256, 2) void gemm_mfma_kernel(
    const _Float16* __restrict__ ph, const _Float16* __restrict__ pl,
    const _Float16* __restrict__ qh, const _Float16* __restrict__ ql,
    const float* __restrict__ alpha_p,
    float* __restrict__ e_out,
    float* __restrict__ rowsum, float* __restrict__ colsum) {
  __shared__ _Float16 Ah[2][128][PADK];
  __shared__ _Float16 Al[2][128][PADK];
  __shared__ _Float16 Bh[2][128][PADK];
  __shared__ _Float16 Bl[2][128][PADK];
  __shared__ float redr[2][128];
  __shared__ float redc[2][128];

  // bijective XCD swizzle over 32*32*4 = 4096 linear blocks
  const int lin = blockIdx.x + 32 * blockIdx.y + 1024 * blockIdx.z;
  const int nid = (lin & 7) * 512 + (lin >> 3);
  const int b = nid >> 10;
  const int rest = nid & 1023;
  const int j0 = (rest & 31) * 128;
  const int i0 = ((rest >> 5) & 31) * 128;

  const int tid = threadIdx.x;
  const int lane = tid & 63;
  const int wave = tid >> 6;
  const int wr = wave >> 1;   // 0..1
  const int wc = wave & 1;    // 0..1

  const size_t tb = (size_t)b * N_ * C_;
  const int srow = tid >> 1;            // 0..127
  const int scol = (tid & 1) * 16;      // 0 or 16
  const _Float16* gAh = ph + tb + (size_t)(i0 + srow) * C_ + scol;
  const _Float16* gAl = pl + tb + (size_t)(i0 + srow) * C_ + scol;
  const _Float16* gBh = qh + tb + (size_t)(j0 + srow) * C_ + scol;
  const _Float16* gBl = ql + tb + (size_t)(j0 + srow) * C_ + scol;

  f32x4 acc_hh[4][4], acc_m[4][4];
#pragma unroll
  for (int m = 0; m < 4; ++m)
#pragma unroll
    for (int n = 0; n < 4; ++n) {
      acc_hh[m][n] = (f32x4){0.f, 0.f, 0.f, 0.f};
      acc_m[m][n] = (f32x4){0.f, 0.f, 0.f, 0.f};
    }

  const int frow = lane & 15;
  const int fko = (lane >> 4) * 8;

  // prologue: stage k-step 0 into buf 0
  {
    f16x8 ra0 = *(const f16x8*)(gAh);
    f16x8 ra1 = *(const f16x8*)(gAh + 8);
    f16x8 rb0 = *(const f16x8*)(gAl);
    f16x8 rb1 = *(const f16x8*)(gAl + 8);
    f16x8 rc0 = *(const f16x8*)(gBh);
    f16x8 rc1 = *(const f16x8*)(gBh + 8);
    f16x8 rd0 = *(const f16x8*)(gBl);
    f16x8 rd1 = *(const f16x8*)(gBl + 8);
    *(f16x8*)&Ah[0][srow][scol] = ra0; *(f16x8*)&Ah[0][srow][scol + 8] = ra1;
    *(f16x8*)&Al[0][srow][scol] = rb0; *(f16x8*)&Al[0][srow][scol + 8] = rb1;
    *(f16x8*)&Bh[0][srow][scol] = rc0; *(f16x8*)&Bh[0][srow][scol + 8] = rc1;
    *(f16x8*)&Bl[0][srow][scol] = rd0; *(f16x8*)&Bl[0][srow][scol + 8] = rd1;
  }

  int buf = 0;
  for (int t = 0; t < 8; ++t) {
    f16x8 ra0, ra1, rb0, rb1, rc0, rc1, rd0, rd1;
    if (t < 7) {
      const int ko = (t + 1) * 32;
      ra0 = *(const f16x8*)(gAh + ko);
      ra1 = *(const f16x8*)(gAh + ko + 8);
      rb0 = *(const f16x8*)(gAl + ko);
      rb1 = *(const f16x8*)(gAl + ko + 8);
      rc0 = *(const f16x8*)(gBh + ko);
      rc1 = *(const f16x8*)(gBh + ko + 8);
      rd0 = *(const f16x8*)(gBl + ko);
      rd1 = *(const f16x8*)(gBl + ko + 8);
    }
    __syncthreads();

    f16x8 fah[4], fal[4];
#pragma unroll
    for (int m = 0; m < 4; ++m) {
      fah[m] = *(const f16x8*)&Ah[buf][wr * 64 + m * 16 + frow][fko];
      fal[m] = *(const f16x8*)&Al[buf][wr * 64 + m * 16 + frow][fko];
    }
    __builtin_amdgcn_s_setprio(1);
#pragma unroll
    for (int n = 0; n < 4; ++n) {
      f16x8 fbh = *(const f16x8*)&Bh[buf][wc * 64 + n * 16 + frow][fko];
      f16x8 fbl = *(const f16x8*)&Bl[buf][wc * 64 + n * 16 + frow][fko];
#pragma unroll
      for (int m = 0; m < 4; ++m) {
        acc_hh[m][n] = __builtin_amdgcn_mfma_f32_16x16x32_f16(fah[m], fbh, acc_hh[m][n], 0, 0, 0);
        acc_m[m][n]  = __builtin_amdgcn_mfma_f32_16x16x32_f16(fah[m], fbl, acc_m[m][n], 0, 0, 0);
        acc_m[m][n]  = __builtin_amdgcn_mfma_f32_16x16x32_f16(fal[m], fbh, acc_m[m][n], 0, 0, 0);
      }
    }
    __builtin_amdgcn_s_setprio(0);

    if (t < 7) {
      const int nb = buf ^ 1;
      *(f16x8*)&Ah[nb][srow][scol] = ra0; *(f16x8*)&Ah[nb][srow][scol + 8] = ra1;
      *(f16x8*)&Al[nb][srow][scol] = rb0; *(f16x8*)&Al[nb][srow][scol + 8] = rb1;
      *(f16x8*)&Bh[nb][srow][scol] = rc0; *(f16x8*)&Bh[nb][srow][scol + 8] = rc1;
      *(f16x8*)&Bl[nb][srow][scol] = rd0; *(f16x8*)&Bl[nb][srow][scol + 8] = rd1;
    }
    buf ^= 1;
  }

  // ---- epilogue: e = exp(alpha*dot); write e; row/col partial sums
  const float al = alpha_p[0];
  float rowp[4][4];
  float colp[4];
#pragma unroll
  for (int m = 0; m < 4; ++m)
#pragma unroll
    for (int r = 0; r < 4; ++r) rowp[m][r] = 0.f;
#pragma unroll
  for (int n = 0; n < 4; ++n) colp[n] = 0.f;

  const int rbase = i0 + wr * 64;
  const int cbase = j0 + wc * 64;
  const int rlane = (lane >> 4) * 4;   // row group from C/D layout
  const int clane = lane & 15;         // col from C/D layout

#pragma unroll
  for (int m = 0; m < 4; ++m)
#pragma unroll
    for (int n = 0; n < 4; ++n) {
      f32x4 dh = acc_hh[m][n];
      f32x4 dm = acc_m[m][n];
#pragma unroll
      for (int reg = 0; reg < 4; ++reg) {
        float dot = dh[reg] + dm[reg] * (1.f / 1024.f);
        float e = __expf(al * dot);
        int row = rbase + m * 16 + rlane + reg;
        int col = cbase + n * 16 + clane;
        e_out[(size_t)(b * N_ + row) * N_ + col] = e;
        rowp[m][reg] += e;
        colp[n] += e;
      }
    }

#pragma unroll
  for (int m = 0; m < 4; ++m)
#pragma unroll
    for (int reg = 0; reg < 4; ++reg) {
      float r = rowp[m][reg];
      r += __shfl_xor(r, 1);
      r += __shfl_xor(r, 2);
      r += __shfl_xor(r, 4);
      r += __shfl_xor(r, 8);
      if (clane == 0) redr[wc][wr * 64 + m * 16 + rlane + reg] = r;
    }
#pragma unroll
  for (int n = 0; n < 4; ++n) {
    float c = colp[n];
    c += __shfl_xor(c, 16);
    c += __shfl_xor(c, 32);
    if (lane < 16) redc[wr][wc * 64 + n * 16 + clane] = c;
  }
  __syncthreads();
  if (tid < 128) {
    atomicAdd(&rowsum[b * N_ + i0 + tid], redr[0][tid] + redr[1][tid]);
    atomicAdd(&colsum[b * N_ + j0 + tid], redc[0][tid] + redc[1][tid]);
  }
}

// ---------------------------------------------------------------------------
// K3: in-place reciprocal of row/col sums (2*B*N contiguous floats).
// ---------------------------------------------------------------------------
__global__ __launch_bounds__(256) void recip_kernel(float* __restrict__ v) {
  int idx = blockIdx.x * 256 + threadIdx.x;
  v[idx] = 1.0f / v[idx];
}

// ---------------------------------------------------------------------------
// Branchless sorted-triple insert: 5 min/max ops.
// ---------------------------------------------------------------------------
__device__ __forceinline__ void top3_insert(float& a0, float& a1, float& a2, float x) {
  float m0 = fmaxf(a0, x);
  float c0 = fminf(a0, x);
  float m1 = fmaxf(a1, c0);
  float c1 = fminf(a1, c0);
  float m2 = fmaxf(a2, c1);
  a0 = m0; a1 = m1; a2 = m2;
}

// ---------------------------------------------------------------------------
// K4: finalize x_c = e*e*invr[i]*invc[j] in place over eq (xc_o_q), transposed
// nontemporal write into xc_o_p, fused per-tile top-3 partials.
// Nontemporal stores use native ext-vector f32x4 (the builtin rejects HIP's
// float4 class type).
// ---------------------------------------------------------------------------
__global__ __launch_bounds__(256) void finalize_kernel(float* __restrict__ eq,
                                                       float* __restrict__ outp,
                                                       const float* __restrict__ invr,
                                                       const float* __restrict__ invc,
                                                       float* __restrict__ rowpart,
                                                       float* __restrict__ colpart) {
  __shared__ float t[64][65];
  __shared__ float cpart[4][64][3];

  const int b = blockIdx.z;
  const int i0 = blockIdx.y * 64;
  const int j0 = blockIdx.x * 64;
  const int tid = threadIdx.x;
  const int tr = tid >> 4;          // 0..15
  const int tc = (tid & 15) << 2;   // 0..60
  const int wave = tid >> 6;
  const int lane = tid & 63;

  float ic0 = invc[b * N_ + j0 + tc + 0];
  float ic1 = invc[b * N_ + j0 + tc + 1];
  float ic2 = invc[b * N_ + j0 + tc + 2];
  float ic3 = invc[b * N_ + j0 + tc + 3];

  float c0a[4], c1a[4], c2a[4];
#pragma unroll
  for (int c = 0; c < 4; ++c) { c0a[c] = -1e30f; c1a[c] = -1e30f; c2a[c] = -1e30f; }

  const size_t basq = (size_t)(b * N_ + i0) * N_ + j0;
#pragma unroll
  for (int rg = 0; rg < 4; ++rg) {
    const int li = rg * 16 + tr;
    const float ir = invr[b * N_ + i0 + li];
    float4 e4 = *(const float4*)(eq + basq + (size_t)li * N_ + tc);
    f32x4 v;
    v.x = e4.x * e4.x * ir * ic0;
    v.y = e4.y * e4.y * ir * ic1;
    v.z = e4.z * e4.z * ir * ic2;
    v.w = e4.w * e4.w * ir * ic3;
    __builtin_nontemporal_store(v, (f32x4*)(eq + basq + (size_t)li * N_ + tc));
    t[tc + 0][li] = v.x;
    t[tc + 1][li] = v.y;
    t[tc + 2][li] = v.z;
    t[tc + 3][li] = v.w;

    float r0 = -1e30f, r1 = -1e30f, r2 = -1e30f;
    top3_insert(r0, r1, r2, v.x);
    top3_insert(r0, r1, r2, v.y);
    top3_insert(r0, r1, r2, v.z);
    top3_insert(r0, r1, r2, v.w);
#pragma unroll
    for (int mask = 1; mask <= 8; mask <<= 1) {
      float b0 = __shfl_xor(r0, mask);
      float b1 = __shfl_xor(r1, mask);
      float b2 = __shfl_xor(r2, mask);
      top3_insert(r0, r1, r2, b0);
      top3_insert(r0, r1, r2, b1);
      top3_insert(r0, r1, r2, b2);
    }
    if ((tid & 15) == 0) {
      const size_t rb = ((size_t)(b * 64 + (j0 >> 6)) * 3) * N_ + i0 + li;
      rowpart[rb] = r0;
      rowpart[rb + N_] = r1;
      rowpart[rb + 2 * (size_t)N_] = r2;
    }

    top3_insert(c0a[0], c1a[0], c2a[0], v.x);
    top3_insert(c0a[1], c1a[1], c2a[1], v.y);
    top3_insert(c0a[2], c1a[2], c2a[2], v.z);
    top3_insert(c0a[3], c1a[3], c2a[3], v.w);
  }

#pragma unroll
  for (int mask = 16; mask <= 32; mask <<= 1) {
#pragma unroll
    for (int c = 0; c < 4; ++c) {
      float b0 = __shfl_xor(c0a[c], mask);
      float b1 = __shfl_xor(c1a[c], mask);
      float b2 = __shfl_xor(c2a[c], mask);
      top3_insert(c0a[c], c1a[c], c2a[c], b0);
      top3_insert(c0a[c], c1a[c], c2a[c], b1);
      top3_insert(c0a[c], c1a[c], c2a[c], b2);
    }
  }
  if (lane < 16) {
#pragma unroll
    for (int c = 0; c < 4; ++c) {
      cpart[wave][tc + c][0] = c0a[c];
      cpart[wave][tc + c][1] = c1a[c];
      cpart[wave][tc + c][2] = c2a[c];
    }
  }

  __syncthreads();

  const size_t basp = (size_t)(b * N_ + j0) * N_ + i0;
#pragma unroll
  for (int cg = 0; cg < 4; ++cg) {
    const int lj = cg * 16 + tr;
    f32x4 v;
    v.x = t[lj][tc + 0];
    v.y = t[lj][tc + 1];
    v.z = t[lj][tc + 2];
    v.w = t[lj][tc + 3];
    __builtin_nontemporal_store(v, (f32x4*)(outp + basp + (size_t)lj * N_ + tc));
  }

  if (tid < 64) {
    float a0 = -1e30f, a1 = -1e30f, a2 = -1e30f;
#pragma unroll
    for (int w = 0; w < 4; ++w) {
      top3_insert(a0, a1, a2, cpart[w][tid][0]);
      top3_insert(a0, a1, a2, cpart[w][tid][1]);
      top3_insert(a0, a1, a2, cpart[w][tid][2]);
    }
    const size_t cb = ((size_t)(b * 64 + (i0 >> 6)) * 3) * N_ + j0 + tid;
    colpart[cb] = a0;
    colpart[cb + N_] = a1;
    colpart[cb + 2 * (size_t)N_] = a2;
  }
}

// ---------------------------------------------------------------------------
// K5: merge 64 per-tile top3 partials per (b, r). Thread-per-output-r,
// fully coalesced.
// ---------------------------------------------------------------------------
__global__ __launch_bounds__(256) void top3_merge_kernel(const float* __restrict__ rowpart,
                                                         const float* __restrict__ colpart,
                                                         float* __restrict__ valp,
                                                         float* __restrict__ valq) {
  const int gid = blockIdx.x * 256 + threadIdx.x;   // 0..32767
  const int which = gid >> 14;        // 0 = rows -> valp, 1 = cols -> valq
  const int rem = gid & 16383;
  const int b = rem >> 12;
  const int r = rem & 4095;
  const float* part = (which ? colpart : rowpart) + (size_t)(b * 64) * 3 * N_ + r;

  float a0 = -1e30f, a1 = -1e30f, a2 = -1e30f;
#pragma unroll 4
  for (int t = 0; t < 192; ++t) {     // 64 tiles x 3 ranks
    top3_insert(a0, a1, a2, part[0]);
    part += N_;
  }
  float* out = which ? valq : valp;
  out[(b * 3 + 0) * N_ + r] = a0;
  out[(b * 3 + 1) * N_ + r] = a1;
  out[(b * 3 + 2) * N_ + r] = a2;
}

// ---------------------------------------------------------------------------
extern "C" void kernel_launch(void* const* d_in, const int* in_sizes, int n_in,
                              void* d_out, int out_size, void* d_ws, size_t ws_size,
                              hipStream_t stream) {
  const float* xp = (const float*)d_in[0];
  const float* xq = (const float*)d_in[1];
  const float* alpha = (const float*)d_in[2];

  float* o = (float*)d_out;
  float* valp = o;                               // [4,3,64,64]
  float* valq = o + 49152;                       // [4,3,64,64]
  float* xcp = o + 98304;                        // [4,4096,64,64]
  float* xcq = o + 98304 + 67108864;             // [4,4096,64,64]

  float* wsf = (float*)d_ws;
  float* rowsum = wsf + 32768;        // 16384
  float* colsum = wsf + 49152;        // 16384
  // fp16 hi/lo buffers (convert->gemm) alias the top3 partial buffers
  // (finalize->merge); lifetimes are disjoint in stream order.
  char* dyn = (char*)(wsf + 65536);
  _Float16* ph = (_Float16*)dyn;                       // 4*4096*256 halves
  _Float16* pl = ph + (size_t)B_ * N_ * C_;
  _Float16* qh = pl + (size_t)B_ * N_ * C_;
  _Float16* ql = qh + (size_t)B_ * N_ * C_;            // total 33.55 MB
  float* rowpart = (float*)dyn;                        // 12.58 MB
  float* colpart = rowpart + 3145728;                  // 12.58 MB

  (void)hipMemsetAsync(rowsum, 0, (size_t)2 * BN_TOT * sizeof(float), stream);

  convert_kernel<<<dim3(N_ / 64, 1, 2 * B_), 256, 0, stream>>>(
      xp, xq, ph, pl, qh, ql);

  gemm_mfma_kernel<<<dim3(N_ / 128, N_ / 128, B_), 256, 0, stream>>>(
      ph, pl, qh, ql, alpha, xcq, rowsum, colsum);

  recip_kernel<<<2 * BN_TOT / 256, 256, 0, stream>>>(rowsum);  // rowsum+colsum contiguous

  finalize_kernel<<<dim3(N_ / 64, N_ / 64, B_), 256, 0, stream>>>(
      xcq, xcp, rowsum, colsum, rowpart, colpart);

  top3_merge_kernel<<<2 * BN_TOT / 256, 256, 0, stream>>>(rowpart, colpart, valp, valq);
}